// Round 10
// baseline (90.724 us; speedup 1.0000x reference)
//
#include <hip/hip_runtime.h>

// Problem: H=W=384, F=K=256. M = 147456 rows.
// out[m,f] = sum_k d[m,k] * y[k,f],  y = x[stations] @ W  (256x256, tiny)
#define FF 256
#define KK 256
#define RR 16                  // rows per stripe
#define STRIPES 4              // stripes per block -> 64 rows/block
#define NBLK 4608              // (147456/64 rowgroups) * 2 col-halves

typedef __attribute__((ext_vector_type(8))) short bf16x8;   // 8 bf16 (4 VGPR)
typedef __attribute__((ext_vector_type(4))) float f32x4;    // MFMA C/D frag

// float -> bf16 bits, round-to-nearest-even
__device__ inline short f2bf(float x) {
    unsigned u = __float_as_uint(x);
    unsigned r = u + 0x7FFFu + ((u >> 16) & 1u);
    return (short)(r >> 16);
}

// Kernel 1: y[k][f] = sum_j x[sx[k],sy[k],j] * W[j][f], stored bf16 in
// FRAGMENT ORDER so kernel-2 B loads are lane-contiguous 16B/lane:
//   idx(k,f) = ((f>>4)*8 + (k>>5))*512 + (((k>>3)&3)*16 + (f&15))*8 + (k&7)
__global__ __launch_bounds__(256) void station_kernel(
        const float* __restrict__ x, const float* __restrict__ W,
        const int* __restrict__ sx, const int* __restrict__ sy,
        short* __restrict__ yp) {
    __shared__ float xrow[FF];
    const int k = blockIdx.x;
    const int f = threadIdx.x;
    const long base = ((long)sx[k] * 384 + (long)sy[k]) * FF;
    xrow[f] = x[base + f];
    __syncthreads();
    float acc = 0.f;
    #pragma unroll 8
    for (int j = 0; j < FF; ++j)
        acc += xrow[j] * W[j * FF + f];   // coalesced across f
    const int idx = ((f >> 4) * 8 + (k >> 5)) * 512
                  + (((k >> 3) & 3) * 16 + (f & 15)) * 8 + (k & 7);
    yp[idx] = f2bf(acc);
}

// Stage one 16-row f32 stripe via global_load_lds (DMA, no VGPR round-trip).
// LDS dest is linear (wave-uniform base + lane*16); the global SOURCE is
// lane-permuted (seg ^= row&7) so that reads can apply the same XOR and be
// bank-conflict-free (rule #21: swizzle source+read, keep dest linear).
__device__ inline void stage_stripe(const float* drow0, float* lbuf,
                                    int wid, int lane) {
    #pragma unroll
    for (int p = 0; p < 4; ++p) {
        const int r = p * 4 + wid;                   // this wave's row
        const float* g = drow0 + (long)r * KK + ((lane ^ (r & 7)) << 2);
        float* l = lbuf + r * KK;                    // wave-uniform base
        __builtin_amdgcn_global_load_lds(
            (const __attribute__((address_space(1))) float*)g,
            (__attribute__((address_space(3))) float*)l, 16, 0, 0);
    }
}

// Kernel 2: 256-thread blocks (4 waves), block = 64 rows x 128 cols.
// A staged as f32 by DMA, double-buffered; raw s_barrier + counted vmcnt(8)
// (never drain to 0) -> no per-stripe pipeline drain. B resident in AGPRs.
__global__ __launch_bounds__(256, 4) void gemm_kernel(
        const float* __restrict__ d, const short* __restrict__ yp,
        float* __restrict__ out) {
    __shared__ __align__(16) float lds[2][RR * KK];   // 2 x 16 KB f32
    const int t    = threadIdx.x;
    const int lane = t & 63;
    const int wid  = t >> 6;          // 0..3: 32-col slice within the half
    const int l15  = lane & 15;
    const int lg   = lane >> 4;       // 0..3: k-subgroup

    // Bijective XCD swizzle (nwg divisible by 8): row-sharing pairs co-XCD.
    const int work = (blockIdx.x & 7) * (NBLK / 8) + (blockIdx.x >> 3);
    const int half = work & 1;                  // col half (128 cols)
    const long mblk = (long)(work >> 1) * (RR * STRIPES);

    // ---- B fragments: 16 x 16B/lane coalesced loads, once per block ----
    bf16x8 bfrag[8][2];
    #pragma unroll
    for (int kf = 0; kf < 8; ++kf)
        #pragma unroll
        for (int nf = 0; nf < 2; ++nf) {
            const int g = half * 8 + wid * 2 + nf;   // 16-col group 0..15
            bfrag[kf][nf] = *(const bf16x8*)(yp + ((g * 8 + kf) << 9) + (lane << 3));
        }
    asm volatile("" :
        "+v"(bfrag[0][0]), "+v"(bfrag[0][1]), "+v"(bfrag[1][0]), "+v"(bfrag[1][1]),
        "+v"(bfrag[2][0]), "+v"(bfrag[2][1]), "+v"(bfrag[3][0]), "+v"(bfrag[3][1]),
        "+v"(bfrag[4][0]), "+v"(bfrag[4][1]), "+v"(bfrag[5][0]), "+v"(bfrag[5][1]),
        "+v"(bfrag[6][0]), "+v"(bfrag[6][1]), "+v"(bfrag[7][0]), "+v"(bfrag[7][1]));

    // ---- prologue: DMA stripe 0, full wait once, barrier ----
    stage_stripe(d + mblk * KK, lds[0], wid, lane);
    asm volatile("s_waitcnt vmcnt(0)" ::: "memory");
    __builtin_amdgcn_s_barrier();
    __builtin_amdgcn_sched_barrier(0);

    const int s7 = l15 & 7;           // read-side XOR (matches source perm)

    for (int s = 0; s < STRIPES; ++s) {
        const long m0 = mblk + (long)s * RR;
        const float* cur = lds[s & 1];

        // (1) issue next stripe's DMA into the other buffer
        if (s + 1 < STRIPES)
            stage_stripe(d + (m0 + RR) * KK, lds[(s + 1) & 1], wid, lane);

        // (2) compute stripe s: A from LDS f32 (XOR'd segs), convert, MFMA
        f32x4 acc[2];
        #pragma unroll
        for (int nf = 0; nf < 2; ++nf)
            #pragma unroll
            for (int q = 0; q < 4; ++q) acc[nf][q] = 0.f;

        #pragma unroll
        for (int kf = 0; kf < 8; ++kf) {
            const int c0 = kf * 8 + lg * 2;           // 16B segment index
            const float4 lo = *(const float4*)(cur + l15 * KK + (((c0    ) ^ s7) << 2));
            const float4 hi = *(const float4*)(cur + l15 * KK + (((c0 + 1) ^ s7) << 2));
            bf16x8 a;
            a[0] = f2bf(lo.x); a[1] = f2bf(lo.y);
            a[2] = f2bf(lo.z); a[3] = f2bf(lo.w);
            a[4] = f2bf(hi.x); a[5] = f2bf(hi.y);
            a[6] = f2bf(hi.z); a[7] = f2bf(hi.w);
            #pragma unroll
            for (int nf = 0; nf < 2; ++nf)
                acc[nf] = __builtin_amdgcn_mfma_f32_16x16x32_bf16(
                              a, bfrag[kf][nf], acc[nf], 0, 0, 0);
        }

        // (3) store C: row = lg*4 + q, col = half*128 + wid*32 + nf*16 + l15
        float* ob = out + m0 * FF + half * 128 + wid * 32;
        #pragma unroll
        for (int nf = 0; nf < 2; ++nf)
            #pragma unroll
            for (int q = 0; q < 4; ++q)
                ob[(long)(lg * 4 + q) * FF + nf * 16 + l15] = acc[nf][q];

        // (4) counted wait: 8 newest vm-ops = this stripe's stores; everything
        // older (next stripe's 4 DMAs, old stores) must have retired.
        // Then raw barrier — NO full drain anywhere in the loop.
        if (s + 1 < STRIPES) {
            asm volatile("s_waitcnt vmcnt(8)" ::: "memory");
            __builtin_amdgcn_s_barrier();
            __builtin_amdgcn_sched_barrier(0);
        }
    }
}

extern "C" void kernel_launch(void* const* d_in, const int* in_sizes, int n_in,
                              void* d_out, int out_size, void* d_ws, size_t ws_size,
                              hipStream_t stream) {
    const float* x  = (const float*)d_in[0];
    const float* d  = (const float*)d_in[1];
    const float* W  = (const float*)d_in[2];
    const int*   sx = (const int*)d_in[3];
    const int*   sy = (const int*)d_in[4];
    float* out = (float*)d_out;
    short* yp  = (short*)d_ws;   // 256*256 bf16 = 128 KB packed fragment buffer

    station_kernel<<<dim3(KK), dim3(FF), 0, stream>>>(x, W, sx, sy, yp);
    gemm_kernel<<<dim3(NBLK), dim3(256), 0, stream>>>(d, yp, out);
}